// Round 1
// baseline (9908.057 us; speedup 1.0000x reference)
//
#include <hip/hip_runtime.h>
#include <cstdint>
#include <cstddef>

#define NT 256

__device__ __forceinline__ float sigf(float v) {
    return 1.0f / (1.0f + __expf(-v));
}

// y = x @ Wl ; r = x @ Wr + b   (per-node dense, weights via uniform scalar loads)
template<int FIN, int FOUT>
__global__ __launch_bounds__(NT)
void xform_k(const float* __restrict__ x, const float* __restrict__ Wl,
             const float* __restrict__ Wr, const float* __restrict__ b,
             float* __restrict__ y, float* __restrict__ r, int n)
{
    int i = blockIdx.x * NT + threadIdx.x;
    if (i >= n) return;
    const float* xr = x + (size_t)i * FIN;
    float h[FIN];
#pragma unroll
    for (int k = 0; k < FIN / 4; ++k) {
        float4 v = reinterpret_cast<const float4*>(xr)[k];
        h[4*k+0] = v.x; h[4*k+1] = v.y; h[4*k+2] = v.z; h[4*k+3] = v.w;
    }
    float ay[FOUT], ar[FOUT];
#pragma unroll
    for (int f = 0; f < FOUT; ++f) { ay[f] = 0.0f; ar[f] = b[f]; }
#pragma unroll
    for (int k = 0; k < FIN; ++k) {
        float xv = h[k];
#pragma unroll
        for (int f = 0; f < FOUT; ++f) {
            ay[f] = fmaf(xv, Wl[k*FOUT + f], ay[f]);
            ar[f] = fmaf(xv, Wr[k*FOUT + f], ar[f]);
        }
    }
    float* yr = y + (size_t)i * 24;   // LD = 24 always
    float* rr = r + (size_t)i * 24;
#pragma unroll
    for (int f = 0; f < FOUT / 4; ++f) {
        reinterpret_cast<float4*>(yr)[f] = make_float4(ay[4*f], ay[4*f+1], ay[4*f+2], ay[4*f+3]);
        reinterpret_cast<float4*>(rr)[f] = make_float4(ar[4*f], ar[4*f+1], ar[4*f+2], ar[4*f+3]);
    }
}

// agg[dst] += y[src] (+ cnt[dst] += 1 when COUNT). y stride fixed 24; agg stride F.
template<int F, bool COUNT>
__global__ __launch_bounds__(NT)
void scat_k(const int* __restrict__ src, const int* __restrict__ dst,
            const float* __restrict__ y, float* agg, float* cnt, int ne)
{
    int e = blockIdx.x * NT + threadIdx.x;
    if (e >= ne) return;
    int s = src[e], d = dst[e];
    const float4* yp = reinterpret_cast<const float4*>(y + (size_t)s * 24);
    float* ap = agg + (size_t)d * F;
#pragma unroll
    for (int k = 0; k < F / 4; ++k) {
        float4 v = yp[k];
        unsafeAtomicAdd(ap + 4*k + 0, v.x);
        unsafeAtomicAdd(ap + 4*k + 1, v.y);
        unsafeAtomicAdd(ap + 4*k + 2, v.z);
        unsafeAtomicAdd(ap + 4*k + 3, v.w);
    }
    if constexpr (COUNT) unsafeAtomicAdd(cnt + d, 1.0f);
}

// h = relu(agg/cnt + rin); y = h @ Wl ; r = h @ Wr + b
// NOTE: y/r may alias agg/rin rows of the same thread (read-then-write in regs) -> no restrict.
template<int FIN, int FOUT>
__global__ __launch_bounds__(NT)
void finx_k(const float* agg, const float* __restrict__ cnt, const float* rin,
            const float* __restrict__ Wl, const float* __restrict__ Wr,
            const float* __restrict__ b, float* y, float* r, int n)
{
    int i = blockIdx.x * NT + threadIdx.x;
    if (i >= n) return;
    float inv = 1.0f / fmaxf(cnt[i], 1.0f);
    const float* ag = agg + (size_t)i * FIN;   // agg stride = FIN (24)
    const float* rg = rin + (size_t)i * 24;    // r stride 24
    float h[FIN];
#pragma unroll
    for (int k = 0; k < FIN / 4; ++k) {
        float4 a4 = reinterpret_cast<const float4*>(ag)[k];
        float4 r4 = reinterpret_cast<const float4*>(rg)[k];
        h[4*k+0] = fmaxf(fmaf(a4.x, inv, r4.x), 0.0f);
        h[4*k+1] = fmaxf(fmaf(a4.y, inv, r4.y), 0.0f);
        h[4*k+2] = fmaxf(fmaf(a4.z, inv, r4.z), 0.0f);
        h[4*k+3] = fmaxf(fmaf(a4.w, inv, r4.w), 0.0f);
    }
    float ay[FOUT], ar[FOUT];
#pragma unroll
    for (int f = 0; f < FOUT; ++f) { ay[f] = 0.0f; ar[f] = b[f]; }
#pragma unroll
    for (int k = 0; k < FIN; ++k) {
        float xv = h[k];
#pragma unroll
        for (int f = 0; f < FOUT; ++f) {
            ay[f] = fmaf(xv, Wl[k*FOUT + f], ay[f]);
            ar[f] = fmaf(xv, Wr[k*FOUT + f], ar[f]);
        }
    }
    float* yr = y + (size_t)i * 24;
    float* rr = r + (size_t)i * 24;
#pragma unroll
    for (int f = 0; f < FOUT / 4; ++f) {
        reinterpret_cast<float4*>(yr)[f] = make_float4(ay[4*f], ay[4*f+1], ay[4*f+2], ay[4*f+3]);
        reinterpret_cast<float4*>(rr)[f] = make_float4(ar[4*f], ar[4*f+1], ar[4*f+2], ar[4*f+3]);
    }
}

// out = sigmoid(agg/cnt + rin)  (agg stride 12, rin stride 24, out stride 12)
__global__ __launch_bounds__(NT)
void fout_k(const float* __restrict__ agg, const float* __restrict__ cnt,
            const float* __restrict__ rin, float* __restrict__ out, int n)
{
    int i = blockIdx.x * NT + threadIdx.x;
    if (i >= n) return;
    float inv = 1.0f / fmaxf(cnt[i], 1.0f);
    const float* ag = agg + (size_t)i * 12;
    const float* rg = rin + (size_t)i * 24;
    float* og = out + (size_t)i * 12;
#pragma unroll
    for (int k = 0; k < 3; ++k) {
        float4 a4 = reinterpret_cast<const float4*>(ag)[k];
        float4 r4 = reinterpret_cast<const float4*>(rg)[k];
        float4 o;
        o.x = sigf(fmaf(a4.x, inv, r4.x));
        o.y = sigf(fmaf(a4.y, inv, r4.y));
        o.z = sigf(fmaf(a4.z, inv, r4.z));
        o.w = sigf(fmaf(a4.w, inv, r4.w));
        reinterpret_cast<float4*>(og)[k] = o;
    }
}

extern "C" void kernel_launch(void* const* d_in, const int* in_sizes, int n_in,
                              void* d_out, int out_size, void* d_ws, size_t ws_size,
                              hipStream_t stream)
{
    const float* x   = (const float*)d_in[0];
    const int*   ei  = (const int*)d_in[1];
    const float* Wl1 = (const float*)d_in[2];
    const float* Wr1 = (const float*)d_in[3];
    const float* b1  = (const float*)d_in[4];
    const float* Wl2 = (const float*)d_in[5];
    const float* Wr2 = (const float*)d_in[6];
    const float* b2  = (const float*)d_in[7];
    const float* Wl3 = (const float*)d_in[8];
    const float* Wr3 = (const float*)d_in[9];
    const float* b3  = (const float*)d_in[10];

    const int N = in_sizes[0] / 32;
    const int E = in_sizes[1] / 2;
    const int* src = ei;
    const int* dst = ei + E;

    float* ws  = (float*)d_ws;
    float* cnt = ws;                        // N
    float* C   = cnt + N;                   // agg1: N*24
    float* D   = C  + (size_t)N * 24;       // agg2: N*24
    float* Eg  = D  + (size_t)N * 24;       // agg3: N*12
    float* A   = Eg + (size_t)N * 12;       // y (stride 24): N*24
    float* B   = A  + (size_t)N * 24;       // r (stride 24): N*24

    // zero cnt + agg1 + agg2 + agg3 (contiguous N*61 floats)
    hipMemsetAsync(d_ws, 0, sizeof(float) * (size_t)N * 61, stream);

    const int nbN = (N + NT - 1) / NT;
    const int nbE = (E + NT - 1) / NT;

    // Layer 1
    xform_k<32, 24><<<nbN, NT, 0, stream>>>(x, Wl1, Wr1, b1, A, B, N);
    scat_k<24, true><<<nbE, NT, 0, stream>>>(src, dst, A, C, cnt, E);
    finx_k<24, 24><<<nbN, NT, 0, stream>>>(C, cnt, B, Wl2, Wr2, b2, A, B, N);
    // Layer 2
    scat_k<24, false><<<nbE, NT, 0, stream>>>(src, dst, A, D, nullptr, E);
    finx_k<24, 12><<<nbN, NT, 0, stream>>>(D, cnt, B, Wl3, Wr3, b3, A, B, N);
    // Layer 3
    scat_k<12, false><<<nbE, NT, 0, stream>>>(src, dst, A, Eg, nullptr, E);
    fout_k<<<nbN, NT, 0, stream>>>(Eg, cnt, B, (float*)d_out, N);
}

// Round 2
// 657.138 us; speedup vs baseline: 15.0776x; 15.0776x over previous
//
#include <hip/hip_runtime.h>
#include <cstdint>
#include <cstddef>

#define NT 256

__device__ __forceinline__ float sigf(float v) {
    return 1.0f / (1.0f + __expf(-v));
}

// ---------------- CSR build ----------------

__global__ __launch_bounds__(NT)
void hist_k(const int* __restrict__ dst, int* deg, int ne)
{
    int e = blockIdx.x * NT + threadIdx.x;
    if (e < ne) atomicAdd(&deg[dst[e]], 1);
}

// block-level exclusive scan of deg -> row_ptr (partial), block sums -> bsum
__global__ __launch_bounds__(NT)
void scan1_k(const int* __restrict__ deg, int* __restrict__ row_ptr,
             int* __restrict__ bsum, int n)
{
    __shared__ int s[NT];
    int t = threadIdx.x;
    int i = blockIdx.x * NT + t;
    int v = (i < n) ? deg[i] : 0;
    s[t] = v;
    __syncthreads();
    for (int off = 1; off < NT; off <<= 1) {
        int add = (t >= off) ? s[t - off] : 0;
        __syncthreads();
        s[t] += add;
        __syncthreads();
    }
    if (i < n) row_ptr[i] = s[t] - v;          // exclusive
    if (t == NT - 1) bsum[blockIdx.x] = s[t];  // inclusive total
}

// single-block exclusive scan of block sums (nb <= 512)
__global__ __launch_bounds__(512)
void scan2_k(int* bsum, int* __restrict__ boff, int nb)
{
    __shared__ int s[512];
    int t = threadIdx.x;
    int v = (t < nb) ? bsum[t] : 0;
    s[t] = v;
    __syncthreads();
    for (int off = 1; off < 512; off <<= 1) {
        int add = (t >= off) ? s[t - off] : 0;
        __syncthreads();
        s[t] += add;
        __syncthreads();
    }
    if (t < nb) boff[t] = s[t] - v;
}

// add block offsets; init cursor; write row_ptr[n] = ne
__global__ __launch_bounds__(NT)
void scan3_k(int* row_ptr, int* __restrict__ cursor,
             const int* __restrict__ boff, int n, int ne)
{
    int i = blockIdx.x * NT + threadIdx.x;
    if (i < n) {
        int rp = row_ptr[i] + boff[blockIdx.x];
        row_ptr[i] = rp;
        cursor[i]  = rp;
    }
    if (i == 0) row_ptr[n] = ne;
}

__global__ __launch_bounds__(NT)
void fill_k(const int* __restrict__ src, const int* __restrict__ dst,
            int* cursor, int* __restrict__ col, int ne)
{
    int e = blockIdx.x * NT + threadIdx.x;
    if (e < ne) {
        int d = dst[e];
        int pos = atomicAdd(&cursor[d], 1);
        col[pos] = src[e];
    }
}

// ---------------- fused gather + SAGE layer ----------------
// 8 lanes per node. Lane g loads float4 #g of each neighbor row (coalesced
// 128B/96B segment per row). Aggregate in regs, stage agg+own-row in LDS
// (group stride padded +4 floats -> conflict-free), then the 8 lanes split
// the FOUT outputs: out[f] = act( mean_agg @ Wl[:,f] + x_i @ Wr[:,f] + b[f] ).
// ACT: 0 = relu, 1 = sigmoid.
template<int FIN, int FOUT, int ACT>
__global__ __launch_bounds__(NT)
void gather_k(const float* __restrict__ Hin, const int* __restrict__ row_ptr,
              const int* __restrict__ col, const float* __restrict__ Wl,
              const float* __restrict__ Wr, const float* __restrict__ b,
              float* __restrict__ Hout, int n)
{
    constexpr int NPB = NT / 8;             // nodes per block (32)
    constexpr int GS  = 2 * FIN + 4;        // padded group stride (floats)
    __shared__ float sm[NPB * GS];

    const int lane8 = threadIdx.x & 7;
    const int grp   = threadIdx.x >> 3;
    const int node  = blockIdx.x * NPB + grp;
    const bool valid  = node < n;
    const bool loader = lane8 < (FIN / 4);

    int rp0 = 0, rp1 = 0;
    if (valid) { rp0 = row_ptr[node]; rp1 = row_ptr[node + 1]; }

    float4 acc = make_float4(0.f, 0.f, 0.f, 0.f);
    float4 xi  = make_float4(0.f, 0.f, 0.f, 0.f);

    if (valid && loader) {
        xi = reinterpret_cast<const float4*>(Hin + (size_t)node * FIN)[lane8];
        int e = rp0;
        for (; e + 1 < rp1; e += 2) {
            int s0 = col[e], s1 = col[e + 1];
            float4 v0 = reinterpret_cast<const float4*>(Hin + (size_t)s0 * FIN)[lane8];
            float4 v1 = reinterpret_cast<const float4*>(Hin + (size_t)s1 * FIN)[lane8];
            acc.x += v0.x; acc.y += v0.y; acc.z += v0.z; acc.w += v0.w;
            acc.x += v1.x; acc.y += v1.y; acc.z += v1.z; acc.w += v1.w;
        }
        if (e < rp1) {
            int s0 = col[e];
            float4 v0 = reinterpret_cast<const float4*>(Hin + (size_t)s0 * FIN)[lane8];
            acc.x += v0.x; acc.y += v0.y; acc.z += v0.z; acc.w += v0.w;
        }
        float invd = 1.0f / fmaxf((float)(rp1 - rp0), 1.0f);
        float* smg = sm + grp * GS;
        smg[4 * lane8 + 0]       = acc.x * invd;
        smg[4 * lane8 + 1]       = acc.y * invd;
        smg[4 * lane8 + 2]       = acc.z * invd;
        smg[4 * lane8 + 3]       = acc.w * invd;
        smg[FIN + 4 * lane8 + 0] = xi.x;
        smg[FIN + 4 * lane8 + 1] = xi.y;
        smg[FIN + 4 * lane8 + 2] = xi.z;
        smg[FIN + 4 * lane8 + 3] = xi.w;
    }
    __syncthreads();

    if (!valid) return;
    const float* smg = sm + grp * GS;
    constexpr int OPL = (FOUT + 7) / 8;     // outputs per lane (strided by 8)
#pragma unroll
    for (int j = 0; j < OPL; ++j) {
        int f = lane8 + 8 * j;
        if (f < FOUT) {
            float a = b[f];
#pragma unroll
            for (int k = 0; k < FIN; ++k) {
                a = fmaf(smg[k],       Wl[k * FOUT + f], a);
                a = fmaf(smg[FIN + k], Wr[k * FOUT + f], a);
            }
            a = (ACT == 0) ? fmaxf(a, 0.0f) : sigf(a);
            Hout[(size_t)node * FOUT + f] = a;
        }
    }
}

extern "C" void kernel_launch(void* const* d_in, const int* in_sizes, int n_in,
                              void* d_out, int out_size, void* d_ws, size_t ws_size,
                              hipStream_t stream)
{
    const float* x   = (const float*)d_in[0];
    const int*   ei  = (const int*)d_in[1];
    const float* Wl1 = (const float*)d_in[2];
    const float* Wr1 = (const float*)d_in[3];
    const float* b1  = (const float*)d_in[4];
    const float* Wl2 = (const float*)d_in[5];
    const float* Wr2 = (const float*)d_in[6];
    const float* b2  = (const float*)d_in[7];
    const float* Wl3 = (const float*)d_in[8];
    const float* Wr3 = (const float*)d_in[9];
    const float* b3  = (const float*)d_in[10];

    const int N = in_sizes[0] / 32;
    const int E = in_sizes[1] / 2;
    const int* src = ei;
    const int* dst = ei + E;

    // ---- workspace layout (ints then 16B-aligned floats) ----
    int* row_ptr = (int*)d_ws;                 // N+1
    int* cursor  = row_ptr + (N + 1);          // N
    int* deg     = cursor + N;                 // N
    int* col     = deg + N;                    // E
    int* bsum    = col + E;                    // 512
    int* boff    = bsum + 512;                 // 512
    size_t int_elems = (size_t)(N + 1) + N + N + E + 1024;
    int_elems = (int_elems + 3) & ~(size_t)3;  // 16B-align the float region
    float* H1 = (float*)d_ws + int_elems;      // N*24
    float* H2 = H1 + (size_t)N * 24;           // N*24

    const int nbE = (E + NT - 1) / NT;
    const int nbN = (N + NT - 1) / NT;         // scan blocks (<=512 required)
    const int nbG = (N + 31) / 32;             // gather blocks (32 nodes/block)

    hipMemsetAsync(deg, 0, sizeof(int) * N, stream);

    // CSR build (shared by all 3 layers)
    hist_k <<<nbE, NT, 0, stream>>>(dst, deg, E);
    scan1_k<<<nbN, NT, 0, stream>>>(deg, row_ptr, bsum, N);
    scan2_k<<<1, 512, 0, stream>>>(bsum, boff, nbN);
    scan3_k<<<nbN, NT, 0, stream>>>(row_ptr, cursor, boff, N, E);
    fill_k <<<nbE, NT, 0, stream>>>(src, dst, cursor, col, E);

    // 3 fused SAGE layers (gather + mean + dual matmul + act)
    gather_k<32, 24, 0><<<nbG, NT, 0, stream>>>(x,  row_ptr, col, Wl1, Wr1, b1, H1, N);
    gather_k<24, 24, 0><<<nbG, NT, 0, stream>>>(H1, row_ptr, col, Wl2, Wr2, b2, H2, N);
    gather_k<24, 12, 1><<<nbG, NT, 0, stream>>>(H2, row_ptr, col, Wl3, Wr3, b3, (float*)d_out, N);
}

// Round 3
// 330.231 us; speedup vs baseline: 30.0034x; 1.9899x over previous
//
#include <hip/hip_runtime.h>
#include <cstdint>
#include <cstddef>

#define NT 256
constexpr int SHIFT = 7;                 // bucket = dst >> 7  (128 nodes/bucket)
constexpr int NBK   = 1024;              // allocated buckets (covers dst < 131072)
constexpr int BMASK = (1 << SHIFT) - 1;  // 127
constexpr int EPB   = 12800;             // edges per partition block (exact: 3.2M/12800=250)

__device__ __forceinline__ float sigf(float v) {
    return 1.0f / (1.0f + __expf(-v));
}

// ---------------- CSR build (no global atomics) ----------------

// per-block bucket histogram -> cnts[bucket * nPB + block]
__global__ __launch_bounds__(NT)
void p1_k(const int* __restrict__ dst, int* __restrict__ cnts, int e_total, int nPB)
{
    __shared__ int h[NBK];
    for (int i = threadIdx.x; i < NBK; i += NT) h[i] = 0;
    __syncthreads();
    int base = blockIdx.x * EPB;
    for (int it = 0; it < EPB / NT; ++it) {
        int e = base + it * NT + threadIdx.x;
        if (e < e_total) atomicAdd(&h[dst[e] >> SHIFT], 1);
    }
    __syncthreads();
    for (int b = threadIdx.x; b < NBK; b += NT)
        cnts[b * nPB + blockIdx.x] = h[b];
}

// exclusive scan, in-place, block partials -> bsum
__global__ __launch_bounds__(NT)
void scan1_k(int* data, int* __restrict__ bsum, int n)
{
    __shared__ int s[NT];
    int t = threadIdx.x;
    int i = blockIdx.x * NT + t;
    int v = (i < n) ? data[i] : 0;
    s[t] = v;
    __syncthreads();
    for (int off = 1; off < NT; off <<= 1) {
        int add = (t >= off) ? s[t - off] : 0;
        __syncthreads();
        s[t] += add;
        __syncthreads();
    }
    if (i < n) data[i] = s[t] - v;
    if (t == NT - 1) bsum[blockIdx.x] = s[t];
}

// single-block exclusive scan of block sums (nb <= 1024)
__global__ __launch_bounds__(1024)
void scan2_k(int* bsum, int* __restrict__ boff, int nb)
{
    __shared__ int s[1024];
    int t = threadIdx.x;
    int v = (t < nb) ? bsum[t] : 0;
    s[t] = v;
    __syncthreads();
    for (int off = 1; off < 1024; off <<= 1) {
        int add = (t >= off) ? s[t - off] : 0;
        __syncthreads();
        s[t] += add;
        __syncthreads();
    }
    if (t < nb) boff[t] = s[t] - v;
}

__global__ __launch_bounds__(NT)
void scan3_k(int* data, const int* __restrict__ boff, int n)
{
    int i = blockIdx.x * NT + threadIdx.x;
    if (i < n) data[i] += boff[blockIdx.x];
}

// partition: part[gbase(bucket,block) + rank] = (src << SHIFT) | (dst & BMASK)
__global__ __launch_bounds__(NT)
void p2_k(const int* __restrict__ src, const int* __restrict__ dst,
          const int* __restrict__ ecnts, unsigned* __restrict__ part,
          int e_total, int nPB)
{
    __shared__ int gb[NBK];
    __shared__ int cur[NBK];
    for (int i = threadIdx.x; i < NBK; i += NT) {
        gb[i]  = ecnts[i * nPB + blockIdx.x];
        cur[i] = 0;
    }
    __syncthreads();
    int base = blockIdx.x * EPB;
    for (int it = 0; it < EPB / NT; ++it) {
        int e = base + it * NT + threadIdx.x;
        if (e < e_total) {
            int d = dst[e];
            int s = src[e];
            int b = d >> SHIFT;
            int r = atomicAdd(&cur[b], 1);
            part[gb[b] + r] = ((unsigned)s << SHIFT) | (unsigned)(d & BMASK);
        }
    }
}

// per-bucket: LDS degree hist + scan -> row_ptr; LDS cursor fill -> col
__global__ __launch_bounds__(NT)
void b_k(const unsigned* __restrict__ part, const int* __restrict__ ecnts,
         int* __restrict__ row_ptr, int* __restrict__ col,
         int nPB, int n, int e_total)
{
    constexpr int NPB2 = 1 << SHIFT;   // 128 nodes per bucket
    __shared__ int deg[NT];
    __shared__ int lrp[NT];
    __shared__ int cur[NPB2];
    const int b  = blockIdx.x;
    const int t  = threadIdx.x;
    const int e0 = ecnts[b * nPB];
    const int e1 = (b + 1 < NBK) ? ecnts[(b + 1) * nPB] : e_total;

    deg[t] = 0;
    __syncthreads();
    for (int e = e0 + t; e < e1; e += NT)
        atomicAdd(&deg[part[e] & BMASK], 1);
    __syncthreads();

    int v = deg[t];
    lrp[t] = v;
    __syncthreads();
    for (int off = 1; off < NT; off <<= 1) {
        int add = (t >= off) ? lrp[t - off] : 0;
        __syncthreads();
        lrp[t] += add;
        __syncthreads();
    }
    int excl = lrp[t] - v;                    // bucket-relative exclusive prefix
    int node = (b << SHIFT) + t;
    if (t < NPB2 + 1 && node <= n) row_ptr[node] = e0 + excl;
    if (t < NPB2) cur[t] = e0 + excl;
    __syncthreads();

    for (int e = e0 + t; e < e1; e += NT) {
        unsigned p = part[e];
        int pos = atomicAdd(&cur[p & BMASK], 1);
        col[pos] = (int)(p >> SHIFT);
    }
}

// ---------------- fused gather + SAGE layer ----------------
template<int FIN, int FOUT, int ACT>
__global__ __launch_bounds__(NT)
void gather_k(const float* __restrict__ Hin, const int* __restrict__ row_ptr,
              const int* __restrict__ col, const float* __restrict__ Wl,
              const float* __restrict__ Wr, const float* __restrict__ b,
              float* __restrict__ Hout, int n)
{
    constexpr int NPB = NT / 8;             // nodes per block (32)
    constexpr int GS  = 2 * FIN + 4;        // padded group stride (floats)
    __shared__ float sm[NPB * GS];

    const int lane8 = threadIdx.x & 7;
    const int grp   = threadIdx.x >> 3;
    const int node  = blockIdx.x * NPB + grp;
    const bool valid  = node < n;
    const bool loader = lane8 < (FIN / 4);

    int rp0 = 0, rp1 = 0;
    if (valid) { rp0 = row_ptr[node]; rp1 = row_ptr[node + 1]; }

    float4 acc = make_float4(0.f, 0.f, 0.f, 0.f);
    float4 xi  = make_float4(0.f, 0.f, 0.f, 0.f);

    if (valid && loader) {
        xi = reinterpret_cast<const float4*>(Hin + (size_t)node * FIN)[lane8];
        int e = rp0;
        for (; e + 1 < rp1; e += 2) {
            int s0 = col[e], s1 = col[e + 1];
            float4 v0 = reinterpret_cast<const float4*>(Hin + (size_t)s0 * FIN)[lane8];
            float4 v1 = reinterpret_cast<const float4*>(Hin + (size_t)s1 * FIN)[lane8];
            acc.x += v0.x; acc.y += v0.y; acc.z += v0.z; acc.w += v0.w;
            acc.x += v1.x; acc.y += v1.y; acc.z += v1.z; acc.w += v1.w;
        }
        if (e < rp1) {
            int s0 = col[e];
            float4 v0 = reinterpret_cast<const float4*>(Hin + (size_t)s0 * FIN)[lane8];
            acc.x += v0.x; acc.y += v0.y; acc.z += v0.z; acc.w += v0.w;
        }
        float invd = 1.0f / fmaxf((float)(rp1 - rp0), 1.0f);
        float* smg = sm + grp * GS;
        smg[4 * lane8 + 0]       = acc.x * invd;
        smg[4 * lane8 + 1]       = acc.y * invd;
        smg[4 * lane8 + 2]       = acc.z * invd;
        smg[4 * lane8 + 3]       = acc.w * invd;
        smg[FIN + 4 * lane8 + 0] = xi.x;
        smg[FIN + 4 * lane8 + 1] = xi.y;
        smg[FIN + 4 * lane8 + 2] = xi.z;
        smg[FIN + 4 * lane8 + 3] = xi.w;
    }
    __syncthreads();

    if (!valid) return;
    const float* smg = sm + grp * GS;
    constexpr int OPL = (FOUT + 7) / 8;     // outputs per lane (strided by 8)
#pragma unroll
    for (int j = 0; j < OPL; ++j) {
        int f = lane8 + 8 * j;
        if (f < FOUT) {
            float a = b[f];
#pragma unroll
            for (int k = 0; k < FIN; ++k) {
                a = fmaf(smg[k],       Wl[k * FOUT + f], a);
                a = fmaf(smg[FIN + k], Wr[k * FOUT + f], a);
            }
            a = (ACT == 0) ? fmaxf(a, 0.0f) : sigf(a);
            Hout[(size_t)node * FOUT + f] = a;
        }
    }
}

extern "C" void kernel_launch(void* const* d_in, const int* in_sizes, int n_in,
                              void* d_out, int out_size, void* d_ws, size_t ws_size,
                              hipStream_t stream)
{
    const float* x   = (const float*)d_in[0];
    const int*   ei  = (const int*)d_in[1];
    const float* Wl1 = (const float*)d_in[2];
    const float* Wr1 = (const float*)d_in[3];
    const float* b1  = (const float*)d_in[4];
    const float* Wl2 = (const float*)d_in[5];
    const float* Wr2 = (const float*)d_in[6];
    const float* b2  = (const float*)d_in[7];
    const float* Wl3 = (const float*)d_in[8];
    const float* Wr3 = (const float*)d_in[9];
    const float* b3  = (const float*)d_in[10];

    const int N = in_sizes[0] / 32;
    const int E = in_sizes[1] / 2;
    const int* src = ei;
    const int* dst = ei + E;

    const int nPB = (E + EPB - 1) / EPB;       // 250 partition blocks
    const int M   = NBK * nPB;                 // cnts elements (256000)
    const int nSB = (M + NT - 1) / NT;         // scan blocks (1000 <= 1024)
    const int nBK = ((N - 1) >> SHIFT) + 1;    // active buckets (782)
    const int nbG = (N + 31) / 32;             // gather blocks

    // ---- workspace layout ----
    int* row_ptr = (int*)d_ws;                 // N+1
    int* cnts    = row_ptr + (N + 2);          // M  (scanned in place -> ecnts)
    int* bsum    = cnts + M;                   // 1024
    int* boff    = bsum + 1024;                // 1024
    int* col     = boff + 1024;                // E
    unsigned* part = (unsigned*)(col + E);     // E
    size_t int_elems = (size_t)(N + 2) + M + 2048 + (size_t)E * 2;
    int_elems = (int_elems + 3) & ~(size_t)3;
    float* H1 = (float*)d_ws + int_elems;      // N*24
    float* H2 = H1 + (size_t)N * 24;           // N*24

    // CSR build, atomic-free at global scope
    p1_k   <<<nPB, NT,   0, stream>>>(dst, cnts, E, nPB);
    scan1_k<<<nSB, NT,   0, stream>>>(cnts, bsum, M);
    scan2_k<<<1,   1024, 0, stream>>>(bsum, boff, nSB);
    scan3_k<<<nSB, NT,   0, stream>>>(cnts, boff, M);
    p2_k   <<<nPB, NT,   0, stream>>>(src, dst, cnts, part, E, nPB);
    b_k    <<<nBK, NT,   0, stream>>>(part, cnts, row_ptr, col, nPB, N, E);

    // 3 fused SAGE layers (gather + mean + dual matmul + act)
    gather_k<32, 24, 0><<<nbG, NT, 0, stream>>>(x,  row_ptr, col, Wl1, Wr1, b1, H1, N);
    gather_k<24, 24, 0><<<nbG, NT, 0, stream>>>(H1, row_ptr, col, Wl2, Wr2, b2, H2, N);
    gather_k<24, 12, 1><<<nbG, NT, 0, stream>>>(H2, row_ptr, col, Wl3, Wr3, b3, (float*)d_out, N);
}

// Round 4
// 266.582 us; speedup vs baseline: 37.1670x; 1.2388x over previous
//
#include <hip/hip_runtime.h>
#include <cstdint>
#include <cstddef>

#define NT 256
constexpr int SHIFT = 7;                 // bucket = dst >> 7  (128 nodes/bucket)
constexpr int NBK   = 1024;              // allocated buckets (covers dst < 131072)
constexpr int BMASK = (1 << SHIFT) - 1;  // 127
constexpr int EPB   = 12800;             // edges per partition block

__device__ __forceinline__ float sigf(float v) {
    return 1.0f / (1.0f + __expf(-v));
}
__device__ __forceinline__ float bf2f(unsigned short u) {
    return __uint_as_float((unsigned)u << 16);
}
__device__ __forceinline__ unsigned short f2bf(float f) {   // round-nearest-even
    unsigned u = __float_as_uint(f);
    return (unsigned short)((u + 0x7fffu + ((u >> 16) & 1u)) >> 16);
}

// ---------------- CSR build (no global atomics) ----------------

__global__ __launch_bounds__(NT)
void p1_k(const int* __restrict__ dst, int* __restrict__ cnts, int e_total, int nPB)
{
    __shared__ int h[NBK];
    for (int i = threadIdx.x; i < NBK; i += NT) h[i] = 0;
    __syncthreads();
    int base = blockIdx.x * EPB;
    for (int it = 0; it < EPB / NT; ++it) {
        int e = base + it * NT + threadIdx.x;
        if (e < e_total) atomicAdd(&h[dst[e] >> SHIFT], 1);
    }
    __syncthreads();
    for (int b = threadIdx.x; b < NBK; b += NT)
        cnts[b * nPB + blockIdx.x] = h[b];
}

__global__ __launch_bounds__(NT)
void scan1_k(int* data, int* __restrict__ bsum, int n)
{
    __shared__ int s[NT];
    int t = threadIdx.x;
    int i = blockIdx.x * NT + t;
    int v = (i < n) ? data[i] : 0;
    s[t] = v;
    __syncthreads();
    for (int off = 1; off < NT; off <<= 1) {
        int add = (t >= off) ? s[t - off] : 0;
        __syncthreads();
        s[t] += add;
        __syncthreads();
    }
    if (i < n) data[i] = s[t] - v;
    if (t == NT - 1) bsum[blockIdx.x] = s[t];
}

__global__ __launch_bounds__(1024)
void scan2_k(int* bsum, int* __restrict__ boff, int nb)
{
    __shared__ int s[1024];
    int t = threadIdx.x;
    int v = (t < nb) ? bsum[t] : 0;
    s[t] = v;
    __syncthreads();
    for (int off = 1; off < 1024; off <<= 1) {
        int add = (t >= off) ? s[t - off] : 0;
        __syncthreads();
        s[t] += add;
        __syncthreads();
    }
    if (t < nb) boff[t] = s[t] - v;
}

__global__ __launch_bounds__(NT)
void scan3_k(int* data, const int* __restrict__ boff, int n)
{
    int i = blockIdx.x * NT + threadIdx.x;
    if (i < n) data[i] += boff[blockIdx.x];
}

__global__ __launch_bounds__(NT)
void p2_k(const int* __restrict__ src, const int* __restrict__ dst,
          const int* __restrict__ ecnts, unsigned* __restrict__ part,
          int e_total, int nPB)
{
    __shared__ int gb[NBK];
    __shared__ int cur[NBK];
    for (int i = threadIdx.x; i < NBK; i += NT) {
        gb[i]  = ecnts[i * nPB + blockIdx.x];
        cur[i] = 0;
    }
    __syncthreads();
    int base = blockIdx.x * EPB;
    for (int it = 0; it < EPB / NT; ++it) {
        int e = base + it * NT + threadIdx.x;
        if (e < e_total) {
            int d = dst[e];
            int s = src[e];
            int b = d >> SHIFT;
            int r = atomicAdd(&cur[b], 1);
            part[gb[b] + r] = ((unsigned)s << SHIFT) | (unsigned)(d & BMASK);
        }
    }
}

__global__ __launch_bounds__(NT)
void b_k(const unsigned* __restrict__ part, const int* __restrict__ ecnts,
         int* __restrict__ row_ptr, int* __restrict__ col,
         int nPB, int n, int e_total)
{
    constexpr int NPB2 = 1 << SHIFT;   // 128 nodes per bucket
    __shared__ int deg[NT];
    __shared__ int lrp[NT];
    __shared__ int cur[NPB2];
    const int b  = blockIdx.x;
    const int t  = threadIdx.x;
    const int e0 = ecnts[b * nPB];
    const int e1 = (b + 1 < NBK) ? ecnts[(b + 1) * nPB] : e_total;

    deg[t] = 0;
    __syncthreads();
    for (int e = e0 + t; e < e1; e += NT)
        atomicAdd(&deg[part[e] & BMASK], 1);
    __syncthreads();

    int v = deg[t];
    lrp[t] = v;
    __syncthreads();
    for (int off = 1; off < NT; off <<= 1) {
        int add = (t >= off) ? lrp[t - off] : 0;
        __syncthreads();
        lrp[t] += add;
        __syncthreads();
    }
    int excl = lrp[t] - v;
    int node = (b << SHIFT) + t;
    if (t < NPB2 + 1 && node <= n) row_ptr[node] = e0 + excl;
    if (t < NPB2) cur[t] = e0 + excl;
    __syncthreads();

    for (int e = e0 + t; e < e1; e += NT) {
        unsigned p = part[e];
        int pos = atomicAdd(&cur[p & BMASK], 1);
        col[pos] = (int)(p >> SHIFT);
    }
}

// ---------------- f32 -> bf16 table conversion (x, stride 32 == storage stride) ----
__global__ __launch_bounds__(NT)
void cvt_k(const float* __restrict__ x, unsigned short* __restrict__ xb, int ntot)
{
    int i = blockIdx.x * NT + threadIdx.x;
    if (i < ntot) xb[i] = f2bf(x[i]);
}

// ---------------- fused gather + SAGE layer (bf16 rows, 64B = 1 line each) ----
// 8 lanes/node; lane l loads ushort4 = features 4l..4l+3 of each neighbor row.
// Rows stored bf16 at stride FS=32 (64B aligned), zero-padded past FIN.
// ACT 0: relu -> bf16 padded rows (stride 32). ACT 1: sigmoid -> f32 (stride FOUT).
template<int FIN, int FOUT, int ACT>
__global__ __launch_bounds__(NT)
void gather_k(const unsigned short* __restrict__ Hin, const int* __restrict__ row_ptr,
              const int* __restrict__ col, const float* __restrict__ Wl,
              const float* __restrict__ Wr, const float* __restrict__ b,
              void* __restrict__ Hout, int n)
{
    constexpr int FS  = 32;                 // storage stride in bf16 elems
    constexpr int NPB = NT / 8;             // 32 nodes per block
    constexpr int GS  = 2 * FS + 4;         // padded LDS group stride (floats)
    __shared__ float sm[NPB * GS];

    const int lane8 = threadIdx.x & 7;
    const int grp   = threadIdx.x >> 3;
    const int node  = blockIdx.x * NPB + grp;
    const bool valid = node < n;

    int rp0 = 0, rp1 = 0;
    if (valid) { rp0 = row_ptr[node]; rp1 = row_ptr[node + 1]; }

    const ushort4* rows = reinterpret_cast<const ushort4*>(Hin);
    float a0 = 0.f, a1 = 0.f, a2 = 0.f, a3 = 0.f;

    if (valid) {
        ushort4 xv = rows[(size_t)node * 8 + lane8];
        int e = rp0;
        for (; e + 3 < rp1; e += 4) {
            int s0 = col[e], s1 = col[e + 1], s2 = col[e + 2], s3 = col[e + 3];
            ushort4 v0 = rows[(size_t)s0 * 8 + lane8];
            ushort4 v1 = rows[(size_t)s1 * 8 + lane8];
            ushort4 v2 = rows[(size_t)s2 * 8 + lane8];
            ushort4 v3 = rows[(size_t)s3 * 8 + lane8];
            a0 += bf2f(v0.x) + bf2f(v1.x) + bf2f(v2.x) + bf2f(v3.x);
            a1 += bf2f(v0.y) + bf2f(v1.y) + bf2f(v2.y) + bf2f(v3.y);
            a2 += bf2f(v0.z) + bf2f(v1.z) + bf2f(v2.z) + bf2f(v3.z);
            a3 += bf2f(v0.w) + bf2f(v1.w) + bf2f(v2.w) + bf2f(v3.w);
        }
        for (; e < rp1; ++e) {
            ushort4 v0 = rows[(size_t)col[e] * 8 + lane8];
            a0 += bf2f(v0.x); a1 += bf2f(v0.y); a2 += bf2f(v0.z); a3 += bf2f(v0.w);
        }
        float invd = 1.0f / fmaxf((float)(rp1 - rp0), 1.0f);
        float* smg = sm + grp * GS;
        smg[4 * lane8 + 0]      = a0 * invd;
        smg[4 * lane8 + 1]      = a1 * invd;
        smg[4 * lane8 + 2]      = a2 * invd;
        smg[4 * lane8 + 3]      = a3 * invd;
        smg[FS + 4 * lane8 + 0] = bf2f(xv.x);
        smg[FS + 4 * lane8 + 1] = bf2f(xv.y);
        smg[FS + 4 * lane8 + 2] = bf2f(xv.z);
        smg[FS + 4 * lane8 + 3] = bf2f(xv.w);
    }
    __syncthreads();

    if (!valid) return;
    const float* smg = sm + grp * GS;

    if constexpr (ACT == 0) {
        unsigned short* out = (unsigned short*)Hout + (size_t)node * FS;
#pragma unroll
        for (int j = 0; j < 4; ++j) {               // f = lane8 + 8j covers 0..31
            int f = lane8 + 8 * j;
            float r = 0.0f;
            if (f < FOUT) {
                float a = b[f];
#pragma unroll
                for (int k = 0; k < FIN; ++k) {
                    a = fmaf(smg[k],      Wl[k * FOUT + f], a);
                    a = fmaf(smg[FS + k], Wr[k * FOUT + f], a);
                }
                r = fmaxf(a, 0.0f);
            }
            out[f] = f2bf(r);                        // zero-pads 24..31
        }
    } else {
        float* out = (float*)Hout + (size_t)node * FOUT;
#pragma unroll
        for (int j = 0; j < (FOUT + 7) / 8; ++j) {
            int f = lane8 + 8 * j;
            if (f < FOUT) {
                float a = b[f];
#pragma unroll
                for (int k = 0; k < FIN; ++k) {
                    a = fmaf(smg[k],      Wl[k * FOUT + f], a);
                    a = fmaf(smg[FS + k], Wr[k * FOUT + f], a);
                }
                out[f] = sigf(a);
            }
        }
    }
}

extern "C" void kernel_launch(void* const* d_in, const int* in_sizes, int n_in,
                              void* d_out, int out_size, void* d_ws, size_t ws_size,
                              hipStream_t stream)
{
    const float* x   = (const float*)d_in[0];
    const int*   ei  = (const int*)d_in[1];
    const float* Wl1 = (const float*)d_in[2];
    const float* Wr1 = (const float*)d_in[3];
    const float* b1  = (const float*)d_in[4];
    const float* Wl2 = (const float*)d_in[5];
    const float* Wr2 = (const float*)d_in[6];
    const float* b2  = (const float*)d_in[7];
    const float* Wl3 = (const float*)d_in[8];
    const float* Wr3 = (const float*)d_in[9];
    const float* b3  = (const float*)d_in[10];

    const int N = in_sizes[0] / 32;
    const int E = in_sizes[1] / 2;
    const int* src = ei;
    const int* dst = ei + E;

    const int nPB = (E + EPB - 1) / EPB;       // partition blocks (250)
    const int M   = NBK * nPB;                 // cnts elements
    const int nSB = (M + NT - 1) / NT;         // scan blocks (<=1024)
    const int nBK = ((N - 1) >> SHIFT) + 1;    // active buckets
    const int nbG = (N + 31) / 32;             // gather blocks
    const int nbC = (N * 32 + NT - 1) / NT;    // cvt blocks

    // ---- workspace layout ----
    int* row_ptr = (int*)d_ws;                 // N+2
    int* cnts    = row_ptr + (N + 2);          // M (scanned in place)
    int* bsum    = cnts + M;                   // 1024
    int* boff    = bsum + 1024;                // 1024
    int* col     = boff + 1024;                // E
    unsigned* part = (unsigned*)(col + E);     // E
    size_t int_elems = (size_t)(N + 2) + M + 2048 + (size_t)E * 2;
    int_elems = (int_elems + 3) & ~(size_t)3;  // 16B align
    unsigned short* xb  = (unsigned short*)((int*)d_ws + int_elems); // N*32 bf16
    unsigned short* H1b = xb  + (size_t)N * 32;                      // N*32 bf16
    unsigned short* H2b = H1b + (size_t)N * 32;                      // N*32 bf16

    // CSR build, atomic-free at global scope
    p1_k   <<<nPB, NT,   0, stream>>>(dst, cnts, E, nPB);
    scan1_k<<<nSB, NT,   0, stream>>>(cnts, bsum, M);
    scan2_k<<<1,   1024, 0, stream>>>(bsum, boff, nSB);
    scan3_k<<<nSB, NT,   0, stream>>>(cnts, boff, M);
    p2_k   <<<nPB, NT,   0, stream>>>(src, dst, cnts, part, E, nPB);
    b_k    <<<nBK, NT,   0, stream>>>(part, cnts, row_ptr, col, nPB, N, E);

    // x -> bf16 table (stride 32 matches storage stride)
    cvt_k  <<<nbC, NT,   0, stream>>>(x, xb, N * 32);

    // 3 fused SAGE layers (1-line-per-edge gathers)
    gather_k<32, 24, 0><<<nbG, NT, 0, stream>>>(xb,  row_ptr, col, Wl1, Wr1, b1, H1b, N);
    gather_k<24, 24, 0><<<nbG, NT, 0, stream>>>(H1b, row_ptr, col, Wl2, Wr2, b2, H2b, N);
    gather_k<24, 12, 1><<<nbG, NT, 0, stream>>>(H2b, row_ptr, col, Wl3, Wr3, b3, (float*)d_out, N);
}

// Round 5
// 263.300 us; speedup vs baseline: 37.6303x; 1.0125x over previous
//
#include <hip/hip_runtime.h>
#include <cstdint>
#include <cstddef>

#define NT 256
constexpr int SHIFT  = 7;                 // bucket = dst >> 7 (128 nodes/bucket)
constexpr int NBK    = 1024;              // allocated buckets
constexpr int BMASK  = (1 << SHIFT) - 1;  // 127
constexpr int EPB    = 12800;             // edges per partition block
constexpr int TSPLIT = 50000;             // src tile split (3.2MB bf16 halves)

__device__ __forceinline__ float sigf(float v) {
    return 1.0f / (1.0f + __expf(-v));
}
__device__ __forceinline__ float bf2f(unsigned short u) {
    return __uint_as_float((unsigned)u << 16);
}
__device__ __forceinline__ unsigned short f2bf(float f) {   // round-nearest-even
    unsigned u = __float_as_uint(f);
    return (unsigned short)((u + 0x7fffu + ((u >> 16) & 1u)) >> 16);
}

// ---------------- CSR build (no global atomics) ----------------

__global__ __launch_bounds__(NT)
void p1_k(const int* __restrict__ dst, int* __restrict__ cnts, int e_total, int nPB)
{
    __shared__ int h[NBK];
    for (int i = threadIdx.x; i < NBK; i += NT) h[i] = 0;
    __syncthreads();
    int base = blockIdx.x * EPB;
    for (int it = 0; it < EPB / NT; ++it) {
        int e = base + it * NT + threadIdx.x;
        if (e < e_total) atomicAdd(&h[dst[e] >> SHIFT], 1);
    }
    __syncthreads();
    for (int b = threadIdx.x; b < NBK; b += NT)
        cnts[b * nPB + blockIdx.x] = h[b];
}

__global__ __launch_bounds__(NT)
void scan1_k(int* data, int* __restrict__ bsum, int n)
{
    __shared__ int s[NT];
    int t = threadIdx.x;
    int i = blockIdx.x * NT + t;
    int v = (i < n) ? data[i] : 0;
    s[t] = v;
    __syncthreads();
    for (int off = 1; off < NT; off <<= 1) {
        int add = (t >= off) ? s[t - off] : 0;
        __syncthreads();
        s[t] += add;
        __syncthreads();
    }
    if (i < n) data[i] = s[t] - v;          // exclusive within chunk
    if (t == NT - 1) bsum[blockIdx.x] = s[t];
}

__global__ __launch_bounds__(1024)
void scan2_k(int* bsum, int* __restrict__ boff, int nb)
{
    __shared__ int s[1024];
    int t = threadIdx.x;
    int v = (t < nb) ? bsum[t] : 0;
    s[t] = v;
    __syncthreads();
    for (int off = 1; off < 1024; off <<= 1) {
        int add = (t >= off) ? s[t - off] : 0;
        __syncthreads();
        s[t] += add;
        __syncthreads();
    }
    if (t < nb) boff[t] = s[t] - v;
}

// partition (adds boff itself; scan3 fused away)
__global__ __launch_bounds__(NT)
void p2_k(const int* __restrict__ src, const int* __restrict__ dst,
          const int* __restrict__ ecnts, const int* __restrict__ boff,
          unsigned* __restrict__ part, int e_total, int nPB)
{
    __shared__ int gb[NBK];
    __shared__ int cur[NBK];
    for (int i = threadIdx.x; i < NBK; i += NT) {
        int g = i * nPB + blockIdx.x;
        gb[i]  = ecnts[g] + boff[g / NT];
        cur[i] = 0;
    }
    __syncthreads();
    int base = blockIdx.x * EPB;
    for (int it = 0; it < EPB / NT; ++it) {
        int e = base + it * NT + threadIdx.x;
        if (e < e_total) {
            int d = dst[e];
            int s = src[e];
            int b = d >> SHIFT;
            int r = atomicAdd(&cur[b], 1);
            part[gb[b] + r] = ((unsigned)s << SHIFT) | (unsigned)(d & BMASK);
        }
    }
}

// per-bucket: dual (tile0/total) histogram + scan -> row_ptr, mptr; 2-cursor fill
__global__ __launch_bounds__(NT)
void b_k(const unsigned* __restrict__ part, const int* __restrict__ ecnts,
         const int* __restrict__ boff, int* __restrict__ row_ptr,
         int* __restrict__ mptr, int* __restrict__ col,
         int nPB, int n, int e_total)
{
    constexpr int NB2 = 1 << SHIFT;   // 128
    __shared__ int d0[NB2], dt[NB2], sc[NB2], c0[NB2], c1[NB2];
    const int b = blockIdx.x;
    const int t = threadIdx.x;
    int g0 = b * nPB;
    const int e0 = ecnts[g0] + boff[g0 / NT];
    int g1 = (b + 1) * nPB;
    const int e1 = ecnts[g1] + boff[g1 / NT];

    if (t < NB2) { d0[t] = 0; dt[t] = 0; }
    __syncthreads();
    for (int e = e0 + t; e < e1; e += NT) {
        unsigned p = part[e];
        int l = p & BMASK;
        int s = (int)(p >> SHIFT);
        atomicAdd(&dt[l], 1);
        if (s < TSPLIT) atomicAdd(&d0[l], 1);
    }
    __syncthreads();
    if (t < NB2) sc[t] = dt[t];
    __syncthreads();
    for (int off = 1; off < NB2; off <<= 1) {
        int add = (t >= off && t < NB2) ? sc[t - off] : 0;
        __syncthreads();
        if (t < NB2) sc[t] += add;
        __syncthreads();
    }
    if (t < NB2) {
        int excl = sc[t] - dt[t];
        int st0  = e0 + excl;
        int node = (b << SHIFT) + t;
        if (node <= n) row_ptr[node] = st0;
        if (node <  n) mptr[node]    = st0 + d0[t];
        c0[t] = st0;
        c1[t] = st0 + d0[t];
    }
    __syncthreads();
    for (int e = e0 + t; e < e1; e += NT) {
        unsigned p = part[e];
        int l = p & BMASK;
        int s = (int)(p >> SHIFT);
        int* cp = (s < TSPLIT) ? &c0[l] : &c1[l];
        int pos = atomicAdd(cp, 1);
        col[pos] = s;
    }
}

// ---------------- f32 -> bf16 table (stride 32) ----------------
__global__ __launch_bounds__(NT)
void cvt_k(const float* __restrict__ x, unsigned short* __restrict__ xb, int ntot)
{
    int i = blockIdx.x * NT + threadIdx.x;
    if (i < ntot) xb[i] = f2bf(x[i]);
}

// ---------------- gather pass A: sum tile-0 neighbors -> P (f32, stride 32) ----
__global__ __launch_bounds__(NT)
void gA_k(const unsigned short* __restrict__ Hin, const int* __restrict__ row_ptr,
          const int* __restrict__ mptr, const int* __restrict__ col,
          float* __restrict__ P, int n)
{
    const int lane8 = threadIdx.x & 7;
    const int grp   = threadIdx.x >> 3;
    const int node  = blockIdx.x * (NT / 8) + grp;
    if (node >= n) return;
    const int e0 = row_ptr[node];
    const int e1 = mptr[node];
    const ushort4* rows = reinterpret_cast<const ushort4*>(Hin);
    float a0 = 0.f, a1 = 0.f, a2 = 0.f, a3 = 0.f;
    int e = e0;
    for (; e + 3 < e1; e += 4) {
        int s0 = col[e], s1 = col[e + 1], s2 = col[e + 2], s3 = col[e + 3];
        ushort4 v0 = rows[(size_t)s0 * 8 + lane8];
        ushort4 v1 = rows[(size_t)s1 * 8 + lane8];
        ushort4 v2 = rows[(size_t)s2 * 8 + lane8];
        ushort4 v3 = rows[(size_t)s3 * 8 + lane8];
        a0 += bf2f(v0.x) + bf2f(v1.x) + bf2f(v2.x) + bf2f(v3.x);
        a1 += bf2f(v0.y) + bf2f(v1.y) + bf2f(v2.y) + bf2f(v3.y);
        a2 += bf2f(v0.z) + bf2f(v1.z) + bf2f(v2.z) + bf2f(v3.z);
        a3 += bf2f(v0.w) + bf2f(v1.w) + bf2f(v2.w) + bf2f(v3.w);
    }
    for (; e < e1; ++e) {
        ushort4 v0 = rows[(size_t)col[e] * 8 + lane8];
        a0 += bf2f(v0.x); a1 += bf2f(v0.y); a2 += bf2f(v0.z); a3 += bf2f(v0.w);
    }
    reinterpret_cast<float4*>(P + (size_t)node * 32)[lane8] = make_float4(a0, a1, a2, a3);
}

// ---------------- gather pass B: + tile-1, mean, self, dual matmul, act ----
template<int FIN, int FOUT, int ACT>
__global__ __launch_bounds__(NT)
void gB_k(const unsigned short* __restrict__ Hin, const int* __restrict__ row_ptr,
          const int* __restrict__ mptr, const int* __restrict__ col,
          const float* __restrict__ P, const float* __restrict__ Wl,
          const float* __restrict__ Wr, const float* __restrict__ b,
          void* __restrict__ Hout, int n)
{
    constexpr int FS  = 32;
    constexpr int NPB = NT / 8;
    constexpr int GS  = 2 * FS + 4;
    __shared__ float sm[NPB * GS];

    const int lane8 = threadIdx.x & 7;
    const int grp   = threadIdx.x >> 3;
    const int node  = blockIdx.x * NPB + grp;
    const bool valid = node < n;

    if (valid) {
        const int rp0 = row_ptr[node];
        const int rpm = mptr[node];
        const int rp1 = row_ptr[node + 1];
        const ushort4* rows = reinterpret_cast<const ushort4*>(Hin);
        float4 pv = reinterpret_cast<const float4*>(P + (size_t)node * 32)[lane8];
        float a0 = pv.x, a1 = pv.y, a2 = pv.z, a3 = pv.w;
        ushort4 xv = rows[(size_t)node * 8 + lane8];
        int e = rpm;
        for (; e + 3 < rp1; e += 4) {
            int s0 = col[e], s1 = col[e + 1], s2 = col[e + 2], s3 = col[e + 3];
            ushort4 v0 = rows[(size_t)s0 * 8 + lane8];
            ushort4 v1 = rows[(size_t)s1 * 8 + lane8];
            ushort4 v2 = rows[(size_t)s2 * 8 + lane8];
            ushort4 v3 = rows[(size_t)s3 * 8 + lane8];
            a0 += bf2f(v0.x) + bf2f(v1.x) + bf2f(v2.x) + bf2f(v3.x);
            a1 += bf2f(v0.y) + bf2f(v1.y) + bf2f(v2.y) + bf2f(v3.y);
            a2 += bf2f(v0.z) + bf2f(v1.z) + bf2f(v2.z) + bf2f(v3.z);
            a3 += bf2f(v0.w) + bf2f(v1.w) + bf2f(v2.w) + bf2f(v3.w);
        }
        for (; e < rp1; ++e) {
            ushort4 v0 = rows[(size_t)col[e] * 8 + lane8];
            a0 += bf2f(v0.x); a1 += bf2f(v0.y); a2 += bf2f(v0.z); a3 += bf2f(v0.w);
        }
        float invd = 1.0f / fmaxf((float)(rp1 - rp0), 1.0f);
        float* smg = sm + grp * GS;
        smg[4 * lane8 + 0]      = a0 * invd;
        smg[4 * lane8 + 1]      = a1 * invd;
        smg[4 * lane8 + 2]      = a2 * invd;
        smg[4 * lane8 + 3]      = a3 * invd;
        smg[FS + 4 * lane8 + 0] = bf2f(xv.x);
        smg[FS + 4 * lane8 + 1] = bf2f(xv.y);
        smg[FS + 4 * lane8 + 2] = bf2f(xv.z);
        smg[FS + 4 * lane8 + 3] = bf2f(xv.w);
    }
    __syncthreads();

    if (!valid) return;
    const float* smg = sm + grp * GS;

    if constexpr (ACT == 0) {
        unsigned short* out = (unsigned short*)Hout + (size_t)node * FS;
#pragma unroll
        for (int j = 0; j < 4; ++j) {
            int f = lane8 + 8 * j;
            float r = 0.0f;
            if (f < FOUT) {
                float a = b[f];
#pragma unroll
                for (int k = 0; k < FIN; ++k) {
                    a = fmaf(smg[k],      Wl[k * FOUT + f], a);
                    a = fmaf(smg[FS + k], Wr[k * FOUT + f], a);
                }
                r = fmaxf(a, 0.0f);
            }
            out[f] = f2bf(r);
        }
    } else {
        float* out = (float*)Hout + (size_t)node * FOUT;
#pragma unroll
        for (int j = 0; j < (FOUT + 7) / 8; ++j) {
            int f = lane8 + 8 * j;
            if (f < FOUT) {
                float a = b[f];
#pragma unroll
                for (int k = 0; k < FIN; ++k) {
                    a = fmaf(smg[k],      Wl[k * FOUT + f], a);
                    a = fmaf(smg[FS + k], Wr[k * FOUT + f], a);
                }
                out[f] = sigf(a);
            }
        }
    }
}

extern "C" void kernel_launch(void* const* d_in, const int* in_sizes, int n_in,
                              void* d_out, int out_size, void* d_ws, size_t ws_size,
                              hipStream_t stream)
{
    const float* x   = (const float*)d_in[0];
    const int*   ei  = (const int*)d_in[1];
    const float* Wl1 = (const float*)d_in[2];
    const float* Wr1 = (const float*)d_in[3];
    const float* b1  = (const float*)d_in[4];
    const float* Wl2 = (const float*)d_in[5];
    const float* Wr2 = (const float*)d_in[6];
    const float* b2  = (const float*)d_in[7];
    const float* Wl3 = (const float*)d_in[8];
    const float* Wr3 = (const float*)d_in[9];
    const float* b3  = (const float*)d_in[10];

    const int N = in_sizes[0] / 32;
    const int E = in_sizes[1] / 2;
    const int* src = ei;
    const int* dst = ei + E;

    const int nPB = (E + EPB - 1) / EPB;       // 250
    const int M   = NBK * nPB;                 // 256000
    const int nSB = (M + NT - 1) / NT;         // 1000 (<=1024)
    const int nBK = ((N - 1) >> SHIFT) + 1;    // 782
    const int nbG = (N + 31) / 32;
    const int nbC = (N * 32 + NT - 1) / NT;

    // ---- workspace layout (16B-aligned float4 regions) ----
    int* row_ptr = (int*)d_ws;                              // N+2
    int* cnts    = row_ptr + (N + 2);                       // M
    int* bsum    = cnts + M;                                // 1024
    int* boff    = bsum + 1024;                             // 1024
    int* mptr    = boff + 1024;                             // N
    size_t off   = (size_t)(N + 2) + M + 2048 + N;
    off = (off + 3) & ~(size_t)3;
    int* col     = (int*)d_ws + off;                        // E
    off += E;                                               // E multiple of 4
    unsigned* part = (unsigned*)((int*)d_ws + off);         // E  (dead after b_k)
    float*    P    = (float*)part;                          // N*32 f32, aliases part
    off += E;
    unsigned short* xb  = (unsigned short*)((int*)d_ws + off); // N*32 bf16
    unsigned short* H1b = xb  + (size_t)N * 32;
    unsigned short* H2b = H1b + (size_t)N * 32;

    // CSR build (scan3 fused into p2/b_k)
    p1_k   <<<nPB, NT,   0, stream>>>(dst, cnts, E, nPB);
    scan1_k<<<nSB, NT,   0, stream>>>(cnts, bsum, M);
    scan2_k<<<1,   1024, 0, stream>>>(bsum, boff, nSB);
    p2_k   <<<nPB, NT,   0, stream>>>(src, dst, cnts, boff, part, E, nPB);
    b_k    <<<nBK, NT,   0, stream>>>(part, cnts, boff, row_ptr, mptr, col, nPB, N, E);

    cvt_k  <<<nbC, NT,   0, stream>>>(x, xb, N * 32);

    // 3 layers x (tile-0 pass, tile-1+finish pass)
    gA_k            <<<nbG, NT, 0, stream>>>(xb,  row_ptr, mptr, col, P, N);
    gB_k<32, 24, 0> <<<nbG, NT, 0, stream>>>(xb,  row_ptr, mptr, col, P, Wl1, Wr1, b1, H1b, N);
    gA_k            <<<nbG, NT, 0, stream>>>(H1b, row_ptr, mptr, col, P, N);
    gB_k<24, 24, 0> <<<nbG, NT, 0, stream>>>(H1b, row_ptr, mptr, col, P, Wl2, Wr2, b2, H2b, N);
    gA_k            <<<nbG, NT, 0, stream>>>(H2b, row_ptr, mptr, col, P, N);
    gB_k<24, 12, 1> <<<nbG, NT, 0, stream>>>(H2b, row_ptr, mptr, col, P, Wl3, Wr3, b3, (float*)d_out, N);
}